// Round 3
// baseline (113.216 us; speedup 1.0000x reference)
//
#include <hip/hip_runtime.h>
#include <hip/hip_fp16.h>

#define KNB 31
#define CH 64
#define TEMP_INV 10.0f   // 1 / temperature(0.1)

typedef _Float16 h2 __attribute__((ext_vector_type(2)));

// ---------------------------------------------------------------------------
// ws layout:
//   bytes [0, 16)        : double ws[2]  (sum(loss*mask), sum(mask))
//   bytes [256, 256+2NC) : __half feature table (fp16 path only)
// ---------------------------------------------------------------------------

__global__ void ch_init_ws(double* __restrict__ ws) {
    ws[0] = 0.0;
    ws[1] = 0.0;
}

// features f32 -> fp16 table, 8 floats per thread
__global__ __launch_bounds__(256) void ch_cvt(
    const float* __restrict__ in, __half* __restrict__ out, int total8)
{
    const int idx = blockIdx.x * blockDim.x + threadIdx.x;
    if (idx >= total8) return;
    const float4* ip = reinterpret_cast<const float4*>(in) + (size_t)idx * 2;
    const float4 a = ip[0];
    const float4 b = ip[1];
    union { uint4 u; __half2 h[4]; } o;
    o.h[0] = __floats2half2_rn(a.x, a.y);
    o.h[1] = __floats2half2_rn(a.z, a.w);
    o.h[2] = __floats2half2_rn(b.x, b.y);
    o.h[3] = __floats2half2_rn(b.z, b.w);
    reinterpret_cast<uint4*>(out)[idx] = o.u;
}

__device__ __forceinline__ float dot2acc(h2 d, float s) {
#if defined(__has_builtin) && __has_builtin(__builtin_amdgcn_fdot2)
    return __builtin_amdgcn_fdot2(d, d, s, false);
#else
    const float x = (float)d[0], y = (float)d[1];
    return s + x * x + y * y;
#endif
}

// 8 lanes per point: lane sub in [0,8) owns 8 channels (16 B).
template <bool FP16>
__global__ __launch_bounds__(256) void ch_main8(
    const float*  __restrict__ feat,    // (N, 64) f32
    const __half* __restrict__ tab,     // (N, 64) fp16 (valid iff FP16)
    const int*    __restrict__ labels,  // (N,)
    const int*    __restrict__ nidx,    // (N, 31)
    double*       __restrict__ ws,
    int n)
{
    const int t   = threadIdx.x;
    const int i   = blockIdx.x * (256 / 8) + (t >> 3);
    const int sub = t & 7;

    float loss_w = 0.0f;
    float pm_f   = 0.0f;

    if (i < n) {
        // ---- own 8-channel fragment -------------------------------------
        union { uint4 u; h2 h[4]; } A;
        float af[8];
        if constexpr (FP16) {
            A.u = *reinterpret_cast<const uint4*>(tab + (size_t)i * CH + sub * 8);
        } else {
            const float4* ap = reinterpret_cast<const float4*>(feat + (size_t)i * CH + sub * 8);
            const float4 v0 = ap[0], v1 = ap[1];
            af[0] = v0.x; af[1] = v0.y; af[2] = v0.z; af[3] = v0.w;
            af[4] = v1.x; af[5] = v1.y; af[6] = v1.z; af[7] = v1.w;
        }

        const int lab = labels[i];

        // ---- phase A: all 31 neighbor indices ---------------------------
        int nj[KNB];
        #pragma unroll
        for (int j = 0; j < KNB; ++j)
            nj[j] = nidx[(size_t)i * KNB + j];

        // ---- phase B: posmask bitmask (independent label gathers) -------
        unsigned pmask = 0u;
        #pragma unroll
        for (int j = 0; j < KNB; ++j)
            pmask |= (labels[nj[j]] == lab) ? (1u << j) : 0u;

        // ---- phase C: 31 independent feature gathers -> dist[] ----------
        float dist[KNB];
        #pragma unroll
        for (int j = 0; j < KNB; ++j) {
            float s = 0.0f;
            if constexpr (FP16) {
                union { uint4 u; h2 h[4]; } B;
                B.u = *reinterpret_cast<const uint4*>(tab + (size_t)nj[j] * CH + sub * 8);
                #pragma unroll
                for (int q = 0; q < 4; ++q) {
                    const h2 d = A.h[q] - B.h[q];
                    s = dot2acc(d, s);
                }
            } else {
                const float4* bp = reinterpret_cast<const float4*>(feat + (size_t)nj[j] * CH + sub * 8);
                const float4 v0 = bp[0], v1 = bp[1];
                float d;
                d = af[0] - v0.x; s += d * d;
                d = af[1] - v0.y; s += d * d;
                d = af[2] - v0.z; s += d * d;
                d = af[3] - v0.w; s += d * d;
                d = af[4] - v1.x; s += d * d;
                d = af[5] - v1.y; s += d * d;
                d = af[6] - v1.z; s += d * d;
                d = af[7] - v1.w; s += d * d;
            }
            // close dist^2 across the 8-lane group
            s += __shfl_xor(s, 1);
            s += __shfl_xor(s, 2);
            s += __shfl_xor(s, 4);
            dist[j] = sqrtf(s) + 1e-8f;
        }

        // ---- phase D: softmax over logits = -dist -----------------------
        float mn = dist[0];
        #pragma unroll
        for (int j = 1; j < KNB; ++j) mn = fminf(mn, dist[j]);

        float se = 0.0f, sp = 0.0f;
        #pragma unroll
        for (int j = 0; j < KNB; ++j) {
            const float e = __expf((mn - dist[j]) * TEMP_INV);
            se += e;
            sp += ((pmask >> j) & 1u) ? e : 0.0f;
        }

        const int cnt = __popc(pmask);
        if (sub == 0 && cnt > 0 && cnt < KNB) {
            loss_w = -logf(sp / se + 1e-8f);
            pm_f   = 1.0f;
        }
    }

    // ---- block reduction, one double atomic per block -------------------
    __shared__ float s_l[256];
    __shared__ float s_c[256];
    s_l[t] = loss_w;
    s_c[t] = pm_f;
    __syncthreads();
    #pragma unroll
    for (int off = 128; off > 0; off >>= 1) {
        if (t < off) {
            s_l[t] += s_l[t + off];
            s_c[t] += s_c[t + off];
        }
        __syncthreads();
    }
    if (t == 0) {
        atomicAdd(ws,     (double)s_l[0]);
        atomicAdd(ws + 1, (double)s_c[0]);
    }
}

__global__ void ch_finalize(const double* __restrict__ ws, float* __restrict__ out) {
    double c = ws[1];
    if (c < 1.0) c = 1.0;
    out[0] = (float)(ws[0] / c);   // WEIGHT = 1.0
}

extern "C" void kernel_launch(void* const* d_in, const int* in_sizes, int n_in,
                              void* d_out, int out_size, void* d_ws, size_t ws_size,
                              hipStream_t stream) {
    const float* feat   = (const float*)d_in[0];
    const int*   labels = (const int*)d_in[1];
    const int*   nidx   = (const int*)d_in[2];
    float*       out    = (float*)d_out;
    double*      ws     = (double*)d_ws;

    const int n = in_sizes[1];                 // N = 100000
    const size_t tab_bytes = (size_t)n * CH * sizeof(__half);
    const bool fp16_ok = ws_size >= 256 + tab_bytes;

    ch_init_ws<<<1, 1, 0, stream>>>(ws);

    const int blocks = (n + 31) / 32;          // 32 points per 256-thread block
    if (fp16_ok) {
        __half* tab = reinterpret_cast<__half*>((char*)d_ws + 256);
        const int total8 = n * CH / 8;
        ch_cvt<<<(total8 + 255) / 256, 256, 0, stream>>>(feat, tab, total8);
        ch_main8<true><<<blocks, 256, 0, stream>>>(feat, tab, labels, nidx, ws, n);
    } else {
        ch_main8<false><<<blocks, 256, 0, stream>>>(feat, nullptr, labels, nidx, ws, n);
    }

    ch_finalize<<<1, 1, 0, stream>>>(ws, out);
}